// Round 3
// baseline (341.981 us; speedup 1.0000x reference)
//
#include <hip/hip_runtime.h>
#include <hip/hip_bf16.h>

// GraphConv: out = sum_a att[a] * (adj_a @ (X@W + b))
// N=8192, A=3, D_IN=256, D_OUT=64. All inputs fp32; output fp32.
// Stacked-K GEMM  C[8192,64] = [adj0|adj1|adj2] @ [att0*S; att1*S; att2*S],
// S = X@W+b in bf16, packed in MFMA-B-fragment order (d_ws).
// R2: 128-row strips (4 waves x 32 rows), 8-way split-K pinned to XCDs via
// bid&7 (each XCD's L2 holds one 384KB B-slice), nt loads on adj only,
// partial-sum workspace + reduce kernel instead of atomics.

#define NNODES 8192
#define DIN    256
#define DOUT   64
#define NA     3
#define KSTACK (NA * NNODES)          // 24576 stacked K
#define KSPLIT 8
#define TILES_PER_SLICE (KSTACK / 32 / KSPLIT)   // 96 k-tiles of 32 per slice
#define STRIP  128
#define NSTRIPS (NNODES / STRIP)      // 64

typedef float f32x4 __attribute__((ext_vector_type(4)));
typedef short s16x8 __attribute__((ext_vector_type(8)));

__device__ __forceinline__ unsigned short f2bf(float f) {
    __hip_bfloat16 h = __float2bfloat16(f);   // hw RNE; compiler packs pairs
    return __builtin_bit_cast(unsigned short, h);
}

// ---------------------------------------------------------------------------
// Kernel 0: zero d_out (atomic fallback path only).
// ---------------------------------------------------------------------------
__global__ __launch_bounds__(256) void zero_out(float* __restrict__ out) {
    f32x4 z = {0.f, 0.f, 0.f, 0.f};
    ((f32x4*)out)[(blockIdx.x << 8) + threadIdx.x] = z;
}

// ---------------------------------------------------------------------------
// Kernel 1: S[m][d] = sum_k X[m][k]*W[k][d] + b[d]; write att[a]*S in packed
// bf16 B-fragment layout: tile (a,kt,nt) holds B[k_local][col] with
// k_local = (lane>>4)*8 + j, col = lane&15; flat = tile*512 + lane*8 + j.
// ---------------------------------------------------------------------------
__global__ __launch_bounds__(256) void prep_support(
    const float* __restrict__ x, const float* __restrict__ w,
    const float* __restrict__ bias, const float* __restrict__ att,
    unsigned short* __restrict__ Bp)
{
    const int t = threadIdx.x;
    const int d = t & 63;
    const int m = (blockIdx.x << 2) + (t >> 6);

    const float* xr = x + (size_t)m * DIN;
    float acc = bias[d];
#pragma unroll 4
    for (int k = 0; k < DIN; k += 4) {
        f32x4 xv = *(const f32x4*)(xr + k);
        acc += xv[0] * w[(k + 0) * DOUT + d];
        acc += xv[1] * w[(k + 1) * DOUT + d];
        acc += xv[2] * w[(k + 2) * DOUT + d];
        acc += xv[3] * w[(k + 3) * DOUT + d];
    }

    const int kt   = m >> 5;
    const int kl   = m & 31;
    const int lane = ((kl >> 3) << 4) | (d & 15);
    const int j    = kl & 7;
    const int nt   = d >> 4;

    const size_t base    = (size_t)(kt * 4 + nt) * 512 + lane * 8 + j;
    const size_t aStride = (size_t)(NNODES / 32) * 4 * 512;  // 524288 elems/adjacency

    const float a0 = att[0], a1 = att[1], a2 = att[2];
    Bp[base]               = f2bf(a0 * acc);
    Bp[base + aStride]     = f2bf(a1 * acc);
    Bp[base + 2 * aStride] = f2bf(a2 * acc);
}

// ---------------------------------------------------------------------------
// Kernel 2: bid = strip*8 + ks. Block = 128 rows x one 3072-k slice.
// Wave w owns rows [strip*128 + w*32, +32) (2 m-frags); all waves walk the
// slice's 96 k-tiles. A: nt fp32 loads -> bf16; B: packed frags (L2-resident
// per XCD). 8 mfma_16x16x32_bf16 per step. No LDS, no cross-wave reduce.
// ---------------------------------------------------------------------------
template <bool ATOMIC>
__global__ __launch_bounds__(256, 2) void graphconv_gemm(
    const float* __restrict__ adj, const unsigned short* __restrict__ Bp,
    float* __restrict__ dst)   // partials base (ATOMIC=false) or out (true)
{
    const int tid  = threadIdx.x;
    const int wave = tid >> 6;
    const int lane = tid & 63;
    const int r    = lane & 15;   // A row within tile / C col
    const int g    = lane >> 4;   // k-subgroup (8 consecutive k's)
    const int ks    = blockIdx.x & 7;
    const int strip = blockIdx.x >> 3;
    const int row0  = strip * STRIP + wave * 32;

    const int kt0 = ks * TILES_PER_SLICE;     // stacked k-tile start

    // per-lane row offsets (elements) for the 2 m-frags
    const size_t roff0 = (size_t)(row0 + r) * NNODES + (g << 3);
    const size_t roff1 = roff0 + (size_t)16 * NNODES;

    const s16x8* __restrict__ bp = (const s16x8*)Bp + (size_t)kt0 * 256 + lane;

    f32x4 acc[2][4];
#pragma unroll
    for (int mf = 0; mf < 2; ++mf)
#pragma unroll
        for (int nt = 0; nt < 4; ++nt)
            acc[mf][nt] = (f32x4){0.f, 0.f, 0.f, 0.f};

#pragma unroll 2
    for (int t = 0; t < TILES_PER_SLICE; ++t) {
        const int kt = kt0 + t;
        // adjacency index + local k-tile (slices cross a-boundaries)
        const float* base = adj + (((size_t)(kt >> 8)) << 26) + ((kt & 255) << 5);

        f32x4 a00 = __builtin_nontemporal_load((const f32x4*)(base + roff0));
        f32x4 a01 = __builtin_nontemporal_load((const f32x4*)(base + roff0 + 4));
        f32x4 a10 = __builtin_nontemporal_load((const f32x4*)(base + roff1));
        f32x4 a11 = __builtin_nontemporal_load((const f32x4*)(base + roff1 + 4));

        s16x8 b0 = bp[0];
        s16x8 b1 = bp[64];
        s16x8 b2 = bp[128];
        s16x8 b3 = bp[192];

        s16x8 af0, af1;
        af0[0] = (short)f2bf(a00[0]); af0[1] = (short)f2bf(a00[1]);
        af0[2] = (short)f2bf(a00[2]); af0[3] = (short)f2bf(a00[3]);
        af0[4] = (short)f2bf(a01[0]); af0[5] = (short)f2bf(a01[1]);
        af0[6] = (short)f2bf(a01[2]); af0[7] = (short)f2bf(a01[3]);
        af1[0] = (short)f2bf(a10[0]); af1[1] = (short)f2bf(a10[1]);
        af1[2] = (short)f2bf(a10[2]); af1[3] = (short)f2bf(a10[3]);
        af1[4] = (short)f2bf(a11[0]); af1[5] = (short)f2bf(a11[1]);
        af1[6] = (short)f2bf(a11[2]); af1[7] = (short)f2bf(a11[3]);

        acc[0][0] = __builtin_amdgcn_mfma_f32_16x16x32_bf16(af0, b0, acc[0][0], 0, 0, 0);
        acc[0][1] = __builtin_amdgcn_mfma_f32_16x16x32_bf16(af0, b1, acc[0][1], 0, 0, 0);
        acc[0][2] = __builtin_amdgcn_mfma_f32_16x16x32_bf16(af0, b2, acc[0][2], 0, 0, 0);
        acc[0][3] = __builtin_amdgcn_mfma_f32_16x16x32_bf16(af0, b3, acc[0][3], 0, 0, 0);
        acc[1][0] = __builtin_amdgcn_mfma_f32_16x16x32_bf16(af1, b0, acc[1][0], 0, 0, 0);
        acc[1][1] = __builtin_amdgcn_mfma_f32_16x16x32_bf16(af1, b1, acc[1][1], 0, 0, 0);
        acc[1][2] = __builtin_amdgcn_mfma_f32_16x16x32_bf16(af1, b2, acc[1][2], 0, 0, 0);
        acc[1][3] = __builtin_amdgcn_mfma_f32_16x16x32_bf16(af1, b3, acc[1][3], 0, 0, 0);

        bp += 256;
    }

    // C/D layout (m89-verified): row = g*4 + j, col = r (per 16x16 tile)
    float* outp = ATOMIC ? dst : dst + (size_t)ks * NNODES * DOUT;
#pragma unroll
    for (int mf = 0; mf < 2; ++mf) {
#pragma unroll
        for (int j = 0; j < 4; ++j) {
            const int rowm = row0 + mf * 16 + (g << 2) + j;
            float* rp = outp + (size_t)rowm * DOUT + r;
#pragma unroll
            for (int nt = 0; nt < 4; ++nt) {
                if (ATOMIC) atomicAdd(rp + nt * 16, acc[mf][nt][j]);
                else        rp[nt * 16] = acc[mf][nt][j];
            }
        }
    }
}

// ---------------------------------------------------------------------------
// Kernel 3: out = sum over 8 k-slice partials.
// ---------------------------------------------------------------------------
__global__ __launch_bounds__(256) void reduce_partials(
    const float* __restrict__ part, float* __restrict__ out)
{
    const int i = (blockIdx.x << 8) + threadIdx.x;    // f32x4 index, 131072 total
    const f32x4* p = (const f32x4*)part;
    f32x4 s = p[i];
#pragma unroll
    for (int ks = 1; ks < KSPLIT; ++ks)
        s += p[i + (size_t)ks * (NNODES * DOUT / 4)];
    ((f32x4*)out)[i] = s;
}

// ---------------------------------------------------------------------------
extern "C" void kernel_launch(void* const* d_in, const int* in_sizes, int n_in,
                              void* d_out, int out_size, void* d_ws, size_t ws_size,
                              hipStream_t stream) {
    const float* x   = (const float*)d_in[0];   // [8192, 256]
    const float* adj = (const float*)d_in[1];   // [3, 8192, 8192]
    const float* att = (const float*)d_in[2];   // [3]
    const float* w   = (const float*)d_in[3];   // [256, 64]
    const float* b   = (const float*)d_in[4];   // [64]
    float* out = (float*)d_out;                 // [8192, 64] fp32

    unsigned short* Bp = (unsigned short*)d_ws; // 3 MB packed bf16 B operand
    const size_t bpBytes  = (size_t)KSTACK * DOUT * 2;            // 3,145,728
    const size_t partOff  = (bpBytes + 255) & ~(size_t)255;
    const size_t partBytes = (size_t)KSPLIT * NNODES * DOUT * 4;  // 16 MB
    const bool usePartials = ws_size >= partOff + partBytes;

    prep_support<<<NNODES / 4, 256, 0, stream>>>(x, w, b, att, Bp);

    if (usePartials) {
        float* part = (float*)((char*)d_ws + partOff);
        graphconv_gemm<false><<<NSTRIPS * KSPLIT, 256, 0, stream>>>(adj, Bp, part);
        reduce_partials<<<NNODES * DOUT / 1024, 256, 0, stream>>>(part, out);
    } else {
        zero_out<<<NNODES * DOUT / 1024, 256, 0, stream>>>(out);
        graphconv_gemm<true><<<NSTRIPS * KSPLIT, 256, 0, stream>>>(adj, Bp, out);
    }
}

// Round 4
// 219.585 us; speedup vs baseline: 1.5574x; 1.5574x over previous
//
#include <hip/hip_runtime.h>
#include <hip/hip_bf16.h>

// GraphConv: out = sum_a att[a] * (adj_a @ (X@W + b))
// N=8192, A=3, D_IN=256, D_OUT=64. fp32 in/out.
// Stacked-K GEMM  C[8192,64] = [adj0|adj1|adj2] @ [att0*S; att1*S; att2*S],
// S = X@W+b in bf16, packed in MFMA-B-fragment order (d_ws).
// R4: LDS-staged A-path. Global adj reads are 1KB-contiguous per instruction
// (sequential 32KB stream per row) instead of 16x 128B scattered segments —
// attacks DRAM page efficiency, the term common to all prior rounds.
// Double-buffered bf16 LDS tile [16][512] (+16B row pad -> conflict-free
// ds_read_b128), loads issued before compute (T14), 4 blocks/CU.

#define NNODES 8192
#define DIN    256
#define DOUT   64
#define NA     3
#define KSTACK (NA * NNODES)          // 24576
#define BK     512
#define NCHUNK (KSTACK / BK)          // 48 (16 per adjacency)
#define STRIP  16
#define LDSROW (BK + 8)               // 520 ushorts: +16B pad = bank phase per row

typedef float f32x4 __attribute__((ext_vector_type(4)));
typedef short s16x8 __attribute__((ext_vector_type(8)));
typedef short s16x4 __attribute__((ext_vector_type(4)));

__device__ __forceinline__ unsigned short f2bf(float f) {
    __hip_bfloat16 h = __float2bfloat16(f);   // hw RNE cvt, compiler packs
    return __builtin_bit_cast(unsigned short, h);
}

__device__ __forceinline__ s16x4 pack4(f32x4 v) {
    s16x4 w;
    w[0] = (short)f2bf(v[0]); w[1] = (short)f2bf(v[1]);
    w[2] = (short)f2bf(v[2]); w[3] = (short)f2bf(v[3]);
    return w;
}

// ---------------------------------------------------------------------------
// Kernel 1: S[m][d] = sum_k X[m][k]*W[k][d] + b[d]; write att[a]*S in packed
// bf16 B-fragment layout: tile (a,kt,nt) holds B[k_local][col] with
// k_local = (lane>>4)*8 + j, col = lane&15; flat = tile*512 + lane*8 + j.
// ---------------------------------------------------------------------------
__global__ __launch_bounds__(256) void prep_support(
    const float* __restrict__ x, const float* __restrict__ w,
    const float* __restrict__ bias, const float* __restrict__ att,
    unsigned short* __restrict__ Bp)
{
    const int t = threadIdx.x;
    const int d = t & 63;
    const int m = (blockIdx.x << 2) + (t >> 6);

    const float* xr = x + (size_t)m * DIN;
    float acc = bias[d];
#pragma unroll 4
    for (int k = 0; k < DIN; k += 4) {
        f32x4 xv = *(const f32x4*)(xr + k);
        acc += xv[0] * w[(k + 0) * DOUT + d];
        acc += xv[1] * w[(k + 1) * DOUT + d];
        acc += xv[2] * w[(k + 2) * DOUT + d];
        acc += xv[3] * w[(k + 3) * DOUT + d];
    }

    const int kt   = m >> 5;
    const int kl   = m & 31;
    const int lane = ((kl >> 3) << 4) | (d & 15);
    const int j    = kl & 7;
    const int nt   = d >> 4;

    const size_t base    = (size_t)(kt * 4 + nt) * 512 + lane * 8 + j;
    const size_t aStride = (size_t)(NNODES / 32) * 4 * 512;  // 524288 elems/adjacency

    const float a0 = att[0], a1 = att[1], a2 = att[2];
    Bp[base]               = f2bf(a0 * acc);
    Bp[base + aStride]     = f2bf(a1 * acc);
    Bp[base + 2 * aStride] = f2bf(a2 * acc);
}

// ---------------------------------------------------------------------------
// Kernel 2: block = 16-row strip, all stacked K. 4 waves split each 512-k
// chunk (128 k = 4 k-tiles per wave). A staged via LDS: per chunk each wave
// loads 4 rows x 512 floats as 1KB-contiguous dwordx4 instructions, cvt to
// bf16, ds_write; fragments read back as conflict-free ds_read_b128.
// B-frags straight from L2 (packed layout). LDS cross-wave reduce, plain
// stores. Double-buffered, loads issued before the MFMA phase.
// ---------------------------------------------------------------------------
__global__ __launch_bounds__(256, 4) void graphconv_gemm(
    const float* __restrict__ adj, const unsigned short* __restrict__ Bp,
    float* __restrict__ out)
{
    __shared__ unsigned short lds[2][STRIP][LDSROW];   // 2 x 16.6 KB

    const int tid  = threadIdx.x;
    const int wave = tid >> 6;
    const int lane = tid & 63;
    const int r    = lane & 15;   // A row within tile / C col
    const int g    = lane >> 4;   // k-subgroup
    const int strip = blockIdx.x;
    const int row0  = strip * STRIP;

    const s16x8* __restrict__ Bv = (const s16x8*)Bp;

    f32x4 acc0 = {0.f, 0.f, 0.f, 0.f};
    f32x4 acc1 = {0.f, 0.f, 0.f, 0.f};
    f32x4 acc2 = {0.f, 0.f, 0.f, 0.f};
    f32x4 acc3 = {0.f, 0.f, 0.f, 0.f};

    // ---- prologue: stage chunk 0 into buffer 0
    {
        const float* ab = adj;   // chunk 0: a=0, col 0
#pragma unroll
        for (int p = 0; p < 4; ++p) {
            const int lr = wave * 4 + p;
            const float* rp = ab + (size_t)(row0 + lr) * NNODES + lane * 4;
            f32x4 v0 = __builtin_nontemporal_load((const f32x4*)rp);
            f32x4 v1 = __builtin_nontemporal_load((const f32x4*)(rp + 256));
            *(s16x4*)&lds[0][lr][lane * 4]       = pack4(v0);
            *(s16x4*)&lds[0][lr][256 + lane * 4] = pack4(v1);
        }
    }

#pragma unroll 2
    for (int c = 0; c < NCHUNK; ++c) {
        __syncthreads();
        const int cur = c & 1;

        // issue global loads for chunk c+1 (hide HBM latency under MFMA)
        f32x4 nv0[4], nv1[4];
        const bool more = (c + 1 < NCHUNK);
        if (more) {
            const int cn = c + 1;
            const float* ab = adj + ((size_t)(cn >> 4) << 26)   // a * N*N
                                  + ((size_t)(cn & 15) << 9);   // (cn%16)*512
#pragma unroll
            for (int p = 0; p < 4; ++p) {
                const int lr = wave * 4 + p;
                const float* rp = ab + (size_t)(row0 + lr) * NNODES + lane * 4;
                nv0[p] = __builtin_nontemporal_load((const f32x4*)rp);
                nv1[p] = __builtin_nontemporal_load((const f32x4*)(rp + 256));
            }
        }

        // compute: wave's k-quarter of this chunk (4 k-tiles of 32)
        const s16x8* bp = Bv + ((size_t)c * 16 + wave * 4) * 256 + lane;
#pragma unroll
        for (int t = 0; t < 4; ++t) {
            const s16x8 af = *(const s16x8*)&lds[cur][r][wave * 128 + t * 32 + g * 8];
            s16x8 b0 = bp[0];
            s16x8 b1 = bp[64];
            s16x8 b2 = bp[128];
            s16x8 b3 = bp[192];
            acc0 = __builtin_amdgcn_mfma_f32_16x16x32_bf16(af, b0, acc0, 0, 0, 0);
            acc1 = __builtin_amdgcn_mfma_f32_16x16x32_bf16(af, b1, acc1, 0, 0, 0);
            acc2 = __builtin_amdgcn_mfma_f32_16x16x32_bf16(af, b2, acc2, 0, 0, 0);
            acc3 = __builtin_amdgcn_mfma_f32_16x16x32_bf16(af, b3, acc3, 0, 0, 0);
            bp += 256;
        }

        // write staged chunk into the other buffer
        if (more) {
#pragma unroll
            for (int p = 0; p < 4; ++p) {
                const int lr = wave * 4 + p;
                *(s16x4*)&lds[cur ^ 1][lr][lane * 4]       = pack4(nv0[p]);
                *(s16x4*)&lds[cur ^ 1][lr][256 + lane * 4] = pack4(nv1[p]);
            }
        }
    }

    // ---- cross-wave reduce: overlay fp32 red[4][16][64] on buffer 0
    __syncthreads();
    float* red = (float*)&lds[0][0][0];
    // C/D layout (m89-verified): per 16x16 tile, col = r, row = g*4 + j
#pragma unroll
    for (int j = 0; j < 4; ++j) {
        const int row = (g << 2) + j;
        float* rp = red + ((wave * 16 + row) << 6) + r;
        rp[0]  = acc0[j];
        rp[16] = acc1[j];
        rp[32] = acc2[j];
        rp[48] = acc3[j];
    }
    __syncthreads();

    const f32x4* redv = (const f32x4*)red;
    f32x4 s = redv[tid] + redv[256 + tid] + redv[512 + tid] + redv[768 + tid];
    ((f32x4*)out)[(strip << 8) + tid] = s;
}

// ---------------------------------------------------------------------------
extern "C" void kernel_launch(void* const* d_in, const int* in_sizes, int n_in,
                              void* d_out, int out_size, void* d_ws, size_t ws_size,
                              hipStream_t stream) {
    const float* x   = (const float*)d_in[0];   // [8192, 256]
    const float* adj = (const float*)d_in[1];   // [3, 8192, 8192]
    const float* att = (const float*)d_in[2];   // [3]
    const float* w   = (const float*)d_in[3];   // [256, 64]
    const float* b   = (const float*)d_in[4];   // [64]
    float* out = (float*)d_out;                 // [8192, 64] fp32
    unsigned short* Bp = (unsigned short*)d_ws; // 3 MB packed bf16 B operand

    prep_support<<<NNODES / 4, 256, 0, stream>>>(x, w, b, att, Bp);
    graphconv_gemm<<<NNODES / STRIP, 256, 0, stream>>>(adj, Bp, out);
}